// Round 1
// baseline (274.774 us; speedup 1.0000x reference)
//
#include <hip/hip_runtime.h>
#include <math.h>

#define BB 8192
#define KK 6
#define EE 5   // K-1
#define CC 1000
#define NV4 250  // CC/4 float4 per row

// ---------------- Kernel A: cross-entropy per (b,k) row --------------------
// One wave (64 lanes) per row of 1000 fp32 logits. Each lane holds up to 4
// float4 (16 floats) in registers: single HBM pass for max + sum-exp.
__global__ __launch_bounds__(256) void ce_kernel(
    const float* __restrict__ yh, const int* __restrict__ ys,
    float* __restrict__ ce)
{
    const int wid  = (blockIdx.x * 256 + threadIdx.x) >> 6;   // row id = b*K+k
    const int lane = threadIdx.x & 63;
    const size_t row = (size_t)wid * CC;
    const float4* rp = (const float4*)(yh + row);

    const float NEG = -__builtin_inff();
    float4 r[4];
#pragma unroll
    for (int i = 0; i < 4; ++i) {
        const int idx = lane + 64 * i;
        if (idx < NV4) r[i] = rp[idx];
        else           r[i] = make_float4(NEG, NEG, NEG, NEG);
    }

    // row max
    float mx = NEG;
#pragma unroll
    for (int i = 0; i < 4; ++i)
        mx = fmaxf(mx, fmaxf(fmaxf(r[i].x, r[i].y), fmaxf(r[i].z, r[i].w)));
#pragma unroll
    for (int off = 32; off > 0; off >>= 1)
        mx = fmaxf(mx, __shfl_xor(mx, off));

    // sum exp(x - max); exp(-inf - mx) = 0 handles the 6 pad slots
    float s = 0.f;
#pragma unroll
    for (int i = 0; i < 4; ++i) {
        s += __expf(r[i].x - mx);
        s += __expf(r[i].y - mx);
        s += __expf(r[i].z - mx);
        s += __expf(r[i].w - mx);
    }
#pragma unroll
    for (int off = 32; off > 0; off >>= 1)
        s += __shfl_xor(s, off);

    // target logit (same address all lanes -> one broadcast load, L1/L2 hit)
    const float xy = yh[row + (size_t)ys[wid]];
    if (lane == 0) ce[wid] = mx + __logf(s) - xy;
}

// ---------------- Kernel B: gating + cost + global reduction ---------------
__global__ __launch_bounds__(256) void gate_kernel(
    const float* __restrict__ ce, const float* __restrict__ g,
    const float* __restrict__ costs, float* __restrict__ out)
{
    const int b = blockIdx.x * 256 + threadIdx.x;   // grid covers exactly BB

    float p = 1.f;       // running prod of (1-g) == p_reach for next exit
    float gs = 0.f;      // gate summation for this sample
    int first = -1;      // first exit with g > 0.5
#pragma unroll
    for (int e = 0; e < EE; ++e) {
        const float ge  = g[b * EE + e];
        const float cee = ce[b * KK + e];
        gs += p * ge * cee;
        if (first < 0 && ge > 0.5f) first = e;
        p *= (1.f - ge);
    }
    gs += p * ce[b * KK + EE];                 // p == p_last here
    const float cost = costs[first >= 0 ? first : EE];
    float contrib = 0.5f * gs + 0.5f * cost;   // (1-ALPHA)=ALPHA=0.5

    // wave reduce
#pragma unroll
    for (int off = 32; off > 0; off >>= 1)
        contrib += __shfl_xor(contrib, off);

    __shared__ float partial[4];
    const int lane = threadIdx.x & 63;
    const int w    = threadIdx.x >> 6;
    if (lane == 0) partial[w] = contrib;
    __syncthreads();
    if (threadIdx.x == 0)
        atomicAdd(out, partial[0] + partial[1] + partial[2] + partial[3]);
}

extern "C" void kernel_launch(void* const* d_in, const int* in_sizes, int n_in,
                              void* d_out, int out_size, void* d_ws, size_t ws_size,
                              hipStream_t stream)
{
    const int*   ys    = (const int*)  d_in[0];
    const float* yh    = (const float*)d_in[1];
    const float* g     = (const float*)d_in[2];
    const float* costs = (const float*)d_in[3];
    float* out = (float*)d_out;
    float* ce  = (float*)d_ws;          // BB*KK floats = 192 KiB scratch

    hipMemsetAsync(d_out, 0, sizeof(float), stream);   // graph-capture safe

    // Kernel A: one wave per row, 4 waves per block
    ce_kernel<<<(BB * KK) / 4, 256, 0, stream>>>(yh, ys, ce);
    // Kernel B: one thread per sample
    gate_kernel<<<BB / 256, 256, 0, stream>>>(ce, g, costs, out);
}